// Round 1
// baseline (488.847 us; speedup 1.0000x reference)
//
#include <hip/hip_runtime.h>
#include <math.h>

#define NN 11
#define BB 4
#define LL 2048
#define DD 1024
#define RR (BB*LL)            // 8192 rows per stream
#define TPB 256
#define EPSV 1e-5f

__device__ __forceinline__ float wave_reduce(float v) {
#pragma unroll
  for (int o = 32; o > 0; o >>= 1) v += __shfl_xor(v, o, 64);
  return v;
}

__device__ __forceinline__ float dot4(const float4 a, const float4 b) {
  return a.x*b.x + a.y*b.y + a.z*b.z + a.w*b.w;
}

// ws layout: wvec[22][DD] floats (q*gamma, attn 0..10 then mlp 0..10),
//            scal[22][2]  floats (sum(q*gamma), sum(q*beta))
__global__ __launch_bounds__(TPB) void prep_kernel(
    const float* __restrict__ aq, const float* __restrict__ ag, const float* __restrict__ ab,
    const float* __restrict__ mq, const float* __restrict__ mg, const float* __restrict__ mb,
    float* __restrict__ wvec, float* __restrict__ scal)
{
  const int j = blockIdx.x;              // 0..21
  const float *q, *g, *bt;
  if (j < NN) { q = aq + (size_t)j*DD;      g = ag + (size_t)j*DD;      bt = ab + (size_t)j*DD; }
  else        { q = mq + (size_t)(j-NN)*DD; g = mg + (size_t)(j-NN)*DD; bt = mb + (size_t)(j-NN)*DD; }
  const int t = threadIdx.x;
  float sqg = 0.f, sqb = 0.f;
  for (int d = t; d < DD; d += TPB) {
    float qq = q[d];
    float w  = qq * g[d];
    wvec[(size_t)j*DD + d] = w;
    sqg += w;
    sqb += qq * bt[d];
  }
  sqg = wave_reduce(sqg);
  sqb = wave_reduce(sqb);
  __shared__ float red[2][TPB/64];
  const int lane = t & 63, wid = t >> 6;
  if (lane == 0) { red[0][wid] = sqg; red[1][wid] = sqb; }
  __syncthreads();
  if (t == 0) {
    float a = 0.f, b2 = 0.f;
    for (int w = 0; w < TPB/64; ++w) { a += red[0][w]; b2 += red[1][w]; }
    scal[2*j]   = a;
    scal[2*j+1] = b2;
  }
}

__global__ __launch_bounds__(TPB) void fused_kernel(
    const float* __restrict__ streams,
    const float* __restrict__ wvec,
    const float* __restrict__ scal,
    float* __restrict__ out)
{
  __shared__ float rows[NN][DD];          // 44 KB: the 11 stream rows for this (b,l)
  __shared__ float s_mu[NN], s_rsig[NN];
  __shared__ float s_dA[NN][NN];          // dot(w_attn[i], streams[n]), i >= n
  __shared__ float s_dM[NN][NN];          // dot(w_mlp[i],  streams[n]), i >  n
  __shared__ float s_red[3][4];

  const int r    = blockIdx.x;            // 0..RR-1  (= b*LL + l)
  const int t    = threadIdx.x;
  const int lane = t & 63;
  const int wid  = t >> 6;

  // ---- load 11 rows into LDS (coalesced float4) ----
#pragma unroll
  for (int n = 0; n < NN; ++n) {
    float4 v = *(const float4*)(streams + ((size_t)n*RR + r)*DD + 4*t);
    *(float4*)&rows[n][4*t] = v;
  }
  __syncthreads();

  // ---- per-wave: row stats + dots with all needed weight vectors ----
  for (int n = wid; n < NN; n += 4) {
    const int c = lane*4;
    float4 x0 = *(const float4*)&rows[n][c +   0];
    float4 x1 = *(const float4*)&rows[n][c + 256];
    float4 x2 = *(const float4*)&rows[n][c + 512];
    float4 x3 = *(const float4*)&rows[n][c + 768];
    float s  = (x0.x+x0.y+x0.z+x0.w) + (x1.x+x1.y+x1.z+x1.w)
             + (x2.x+x2.y+x2.z+x2.w) + (x3.x+x3.y+x3.z+x3.w);
    float ss = dot4(x0,x0) + dot4(x1,x1) + dot4(x2,x2) + dot4(x3,x3);
    s  = wave_reduce(s);
    ss = wave_reduce(ss);
    if (lane == 0) {
      float mu  = s * (1.f/DD);
      float var = ss * (1.f/DD) - mu*mu;
      s_mu[n]   = mu;
      s_rsig[n] = rsqrtf(var + EPSV);
    }
    for (int i = n; i < NN; ++i) {        // attn dots
      const float* wp = wvec + (size_t)i*DD + c;
      float d = dot4(x0, *(const float4*)(wp))
              + dot4(x1, *(const float4*)(wp+256))
              + dot4(x2, *(const float4*)(wp+512))
              + dot4(x3, *(const float4*)(wp+768));
      d = wave_reduce(d);
      if (lane == 0) s_dA[i][n] = d;
    }
    for (int i = n+1; i < NN; ++i) {      // mlp dots (original streams only for n<i)
      const float* wp = wvec + (size_t)(NN+i)*DD + c;
      float d = dot4(x0, *(const float4*)(wp))
              + dot4(x1, *(const float4*)(wp+256))
              + dot4(x2, *(const float4*)(wp+512))
              + dot4(x3, *(const float4*)(wp+768));
      d = wave_reduce(d);
      if (lane == 0) s_dM[i][n] = d;
    }
  }
  __syncthreads();

  const size_t dcol = (size_t)r*DD + 4*t;

  for (int i = 0; i < NN; ++i) {
    const float qgA = scal[2*i], qbA = scal[2*i+1];

    // ---- pass 1: softmax over n=0..i, weighted sum -> h (registers) ----
    float mx = -3.0e38f;
    for (int n = 0; n <= i; ++n) {
      float lg = (s_dA[i][n] - s_mu[n]*qgA) * s_rsig[n] + qbA;
      mx = fmaxf(mx, lg);
    }
    float ssum = 0.f;
    float4 h = make_float4(0.f,0.f,0.f,0.f);
    for (int n = 0; n <= i; ++n) {
      float lg = (s_dA[i][n] - s_mu[n]*qgA) * s_rsig[n] + qbA;
      float e  = __expf(lg - mx);
      ssum += e;
      float4 v = *(const float4*)&rows[n][4*t];
      h.x += e*v.x; h.y += e*v.y; h.z += e*v.z; h.w += e*v.w;
    }
    const float inv = 1.f / ssum;
    h.x *= inv; h.y *= inv; h.z *= inv; h.w *= inv;

    // ---- h stats (block reduce: sum, sumsq, dot with w_mlp[i]) ----
    float hs  = h.x + h.y + h.z + h.w;
    float hss = dot4(h, h);
    const float4 wm = *(const float4*)(wvec + (size_t)(NN+i)*DD + 4*t);
    float hd  = dot4(h, wm);
    hs  = wave_reduce(hs);
    hss = wave_reduce(hss);
    hd  = wave_reduce(hd);
    if (lane == 0) { s_red[0][wid] = hs; s_red[1][wid] = hss; s_red[2][wid] = hd; }
    __syncthreads();
    hs  = s_red[0][0] + s_red[0][1] + s_red[0][2] + s_red[0][3];
    hss = s_red[1][0] + s_red[1][1] + s_red[1][2] + s_red[1][3];
    hd  = s_red[2][0] + s_red[2][1] + s_red[2][2] + s_red[2][3];

    const float qgM = scal[2*(NN+i)], qbM = scal[2*(NN+i)+1];
    const float muh  = hs * (1.f/DD);
    const float varh = hss * (1.f/DD) - muh*muh;
    const float rsh  = rsqrtf(varh + EPSV);
    const float lgh  = (hd - muh*qgM) * rsh + qbM;

    // ---- pass 2: softmax over {streams[0..i-1], h}, weighted sum -> out[i] ----
    float mx2 = lgh;
    for (int n = 0; n < i; ++n) {
      float lg = (s_dM[i][n] - s_mu[n]*qgM) * s_rsig[n] + qbM;
      mx2 = fmaxf(mx2, lg);
    }
    float ssum2 = 0.f;
    float4 o = make_float4(0.f,0.f,0.f,0.f);
    for (int n = 0; n < i; ++n) {
      float lg = (s_dM[i][n] - s_mu[n]*qgM) * s_rsig[n] + qbM;
      float e  = __expf(lg - mx2);
      ssum2 += e;
      float4 v = *(const float4*)&rows[n][4*t];
      o.x += e*v.x; o.y += e*v.y; o.z += e*v.z; o.w += e*v.w;
    }
    float eh = __expf(lgh - mx2);
    ssum2 += eh;
    o.x += eh*h.x; o.y += eh*h.y; o.z += eh*h.z; o.w += eh*h.w;
    const float inv2 = 1.f / ssum2;
    o.x *= inv2; o.y *= inv2; o.z *= inv2; o.w *= inv2;

    *(float4*)(out + (size_t)i*RR*DD + dcol) = o;
    __syncthreads();   // protect s_red reuse next iteration
  }
}

extern "C" void kernel_launch(void* const* d_in, const int* in_sizes, int n_in,
                              void* d_out, int out_size, void* d_ws, size_t ws_size,
                              hipStream_t stream) {
  const float* streams = (const float*)d_in[0];
  const float* aq = (const float*)d_in[1];
  const float* ag = (const float*)d_in[2];
  const float* ab = (const float*)d_in[3];
  const float* mq = (const float*)d_in[4];
  const float* mg = (const float*)d_in[5];
  const float* mb = (const float*)d_in[6];
  float* outp = (float*)d_out;
  float* wvec = (float*)d_ws;               // 22*1024 floats
  float* scal = wvec + 2*NN*DD;             // 44 floats
  prep_kernel<<<dim3(2*NN), dim3(TPB), 0, stream>>>(aq, ag, ab, mq, mg, mb, wvec, scal);
  fused_kernel<<<dim3(RR), dim3(TPB), 0, stream>>>(streams, wvec, scal, outp);
}

// Round 2
// 486.962 us; speedup vs baseline: 1.0039x; 1.0039x over previous
//
#include <hip/hip_runtime.h>
#include <math.h>

#define NN 11
#define BB 4
#define LL 2048
#define DD 1024
#define RR (BB*LL)            // 8192 positions
#define EPSV 1e-5f
#define PREP_TPB 256
#define K1_TPB 128
#define K3_TPB 256
#define CSTRIDE 128

// flat LDS slot map for the 209 per-position scalars (padded layout)
#define IA(i,n) ((i)*11+(n))          // attn dots, n<=i      -> 0..120
#define IM(i,n) (121+(i)*11+(n))      // mlp dots,  n<=i      -> 121..241
#define IG(m,n) (242+(m)*11+(n))      // gram, m<=n           -> 242..362
#define IS(n)   (363+(n))             // row sums             -> 363..373
#define NSLOT 374

__device__ __forceinline__ float wave_reduce(float v) {
#pragma unroll
  for (int o = 32; o > 0; o >>= 1) v += __shfl_xor(v, o, 64);
  return v;
}

__device__ __forceinline__ float dot4(const float4 a, const float4 b) {
  return a.x*b.x + a.y*b.y + a.z*b.z + a.w*b.w;
}

// ws: wvec[22][DD] (q*gamma), scal[22][2] (sum(q*g), sum(q*b)), then C[RR][128]
__global__ __launch_bounds__(PREP_TPB) void prep_kernel(
    const float* __restrict__ aq, const float* __restrict__ ag, const float* __restrict__ ab,
    const float* __restrict__ mq, const float* __restrict__ mg, const float* __restrict__ mb,
    float* __restrict__ wvec, float* __restrict__ scal)
{
  const int j = blockIdx.x;              // 0..21
  const float *q, *g, *bt;
  if (j < NN) { q = aq + (size_t)j*DD;      g = ag + (size_t)j*DD;      bt = ab + (size_t)j*DD; }
  else        { q = mq + (size_t)(j-NN)*DD; g = mg + (size_t)(j-NN)*DD; bt = mb + (size_t)(j-NN)*DD; }
  const int t = threadIdx.x;
  float sqg = 0.f, sqb = 0.f;
  for (int d = t; d < DD; d += PREP_TPB) {
    float qq = q[d];
    float w  = qq * g[d];
    wvec[(size_t)j*DD + d] = w;
    sqg += w;
    sqb += qq * bt[d];
  }
  sqg = wave_reduce(sqg);
  sqb = wave_reduce(sqb);
  __shared__ float red[2][PREP_TPB/64];
  const int lane = t & 63, wid = t >> 6;
  if (lane == 0) { red[0][wid] = sqg; red[1][wid] = sqb; }
  __syncthreads();
  if (t == 0) {
    float a = 0.f, b2 = 0.f;
    for (int w = 0; w < PREP_TPB/64; ++w) { a += red[0][w]; b2 += red[1][w]; }
    scal[2*j]   = a;
    scal[2*j+1] = b2;
  }
}

// K1: per position compute 209 scalars, then the 11x11 coefficient matrix C.
__global__ __launch_bounds__(K1_TPB) void pos_kernel(
    const float* __restrict__ streams,
    const float* __restrict__ wvec,
    const float* __restrict__ scal,
    float* __restrict__ Cmat)
{
  __shared__ float red[2][NSLOT];
  __shared__ float fin[NSLOT];
  __shared__ float fmu[NN], frs[NN];

  const int p    = blockIdx.x;           // position 0..RR-1
  const int t    = threadIdx.x;
  const int lane = t & 63;
  const int w    = t >> 6;
  const int c    = 4*t;                  // 0..508; thread owns d in {c..c+3, 512+c..512+c+3}

  float4 xa[NN], xb[NN];
#pragma unroll
  for (int n = 0; n < NN; ++n) {
    const float* base = streams + ((size_t)n*RR + p)*DD + c;
    xa[n] = *(const float4*)(base);
    xb[n] = *(const float4*)(base + 512);
  }

  // ---- row sums (11 reduces) ----
  {
    float v[NN];
#pragma unroll
    for (int n = 0; n < NN; ++n)
      v[n] = (xa[n].x+xa[n].y+xa[n].z+xa[n].w) + (xb[n].x+xb[n].y+xb[n].z+xb[n].w);
#pragma unroll
    for (int n = 0; n < NN; ++n) v[n] = wave_reduce(v[n]);
    if (lane == 0) {
#pragma unroll
      for (int n = 0; n < NN; ++n) red[w][IS(n)] = v[n];
    }
  }

  // ---- Gram matrix, m<=n (66 reduces) ----
  for (int m = 0; m < NN; ++m) {         // runtime m: uniform branches below are free
    float v[NN];
#pragma unroll
    for (int n = 0; n < NN; ++n) if (n >= m) v[n] = dot4(xa[n],xa[m]) + dot4(xb[n],xb[m]);
#pragma unroll
    for (int n = 0; n < NN; ++n) if (n >= m) v[n] = wave_reduce(v[n]);
    if (lane == 0) {
#pragma unroll
      for (int n = 0; n < NN; ++n) if (n >= m) red[w][IG(m,n)] = v[n];
    }
  }

  // ---- dots with the 22 weight vectors, n<=i (132 reduces) ----
  for (int jj = 0; jj < 2*NN; ++jj) {
    const int ii = (jj < NN) ? jj : (jj - NN);
    const float* wp = wvec + (size_t)jj*DD + c;
    float4 wa = *(const float4*)(wp);
    float4 wb = *(const float4*)(wp + 512);
    float v[NN];
#pragma unroll
    for (int n = 0; n < NN; ++n) if (n <= ii) v[n] = dot4(xa[n],wa) + dot4(xb[n],wb);
#pragma unroll
    for (int n = 0; n < NN; ++n) if (n <= ii) v[n] = wave_reduce(v[n]);
    if (lane == 0) {
      if (jj < NN) {
#pragma unroll
        for (int n = 0; n < NN; ++n) if (n <= ii) red[w][IA(ii,n)] = v[n];
      } else {
#pragma unroll
        for (int n = 0; n < NN; ++n) if (n <= ii) red[w][IM(ii,n)] = v[n];
      }
    }
  }
  __syncthreads();
  for (int s = t; s < NSLOT; s += K1_TPB) fin[s] = red[0][s] + red[1][s];
  __syncthreads();
  if (t < NN) {
    float mu  = fin[IS(t)] * (1.0f/DD);
    float var = fin[IG(t,t)] * (1.0f/DD) - mu*mu;
    fmu[t] = mu;
    frs[t] = rsqrtf(var + EPSV);
  }
  __syncthreads();

  // ---- scalar phase: lane i computes coefficient row C[i][*] ----
  if (t < NN) {
    const int i = t;
    const float qgA = scal[2*i],        qbA = scal[2*i+1];
    const float qgM = scal[2*(NN+i)],   qbM = scal[2*(NN+i)+1];

    // pass 1 softmax over n<=i
    float w1[NN];
    float mx = -3.0e38f;
#pragma unroll
    for (int n = 0; n < NN; ++n) if (n <= i) {
      float lg = (fin[IA(i,n)] - fmu[n]*qgA)*frs[n] + qbA;
      w1[n] = lg;
      mx = fmaxf(mx, lg);
    }
    float S = 0.f;
#pragma unroll
    for (int n = 0; n < NN; ++n) if (n <= i) { float e = __expf(w1[n]-mx); w1[n] = e; S += e; }
    float inv = 1.f/S;
#pragma unroll
    for (int n = 0; n < NN; ++n) if (n <= i) w1[n] *= inv;

    // h statistics via linearity + Gram
    float mu_h = 0.f, hd = 0.f, msq = 0.f;
#pragma unroll
    for (int n = 0; n < NN; ++n) if (n <= i) {
      mu_h += w1[n]*fmu[n];
      hd   += w1[n]*fin[IM(i,n)];
      msq  += w1[n]*w1[n]*fin[IG(n,n)];
    }
#pragma unroll
    for (int m = 0; m < NN; ++m) if (m < i) {
#pragma unroll
      for (int n = m+1; n < NN; ++n) if (n <= i) msq += 2.f*w1[m]*w1[n]*fin[IG(m,n)];
    }
    float var_h = msq*(1.0f/DD) - mu_h*mu_h;
    float rsh   = rsqrtf(var_h + EPSV);
    float lgh   = (hd - mu_h*qgM)*rsh + qbM;

    // pass 2 softmax over {streams[0..i-1], h}
    float w2[NN];
    float mx2 = lgh;
#pragma unroll
    for (int n = 0; n < NN; ++n) if (n < i) {
      float lg = (fin[IM(i,n)] - fmu[n]*qgM)*frs[n] + qbM;
      w2[n] = lg;
      mx2 = fmaxf(mx2, lg);
    }
    float eh = __expf(lgh - mx2);
    float S2 = eh;
#pragma unroll
    for (int n = 0; n < NN; ++n) if (n < i) { float e = __expf(w2[n]-mx2); w2[n] = e; S2 += e; }
    float inv2 = 1.f/S2;
    float ehw  = eh*inv2;

    float* crow = Cmat + (size_t)p*CSTRIDE + i*NN;
#pragma unroll
    for (int n = 0; n < NN; ++n) {
      float cc;
      if (n < i)       cc = w2[n]*inv2 + ehw*w1[n];
      else if (n == i) cc = ehw*w1[n];
      else             cc = 0.f;
      crow[n] = cc;
    }
  }
}

// K3: pure streaming combine out[i] = sum_n C[i][n] * x[n]
__global__ __launch_bounds__(K3_TPB) void combine_kernel(
    const float* __restrict__ streams,
    const float* __restrict__ Cmat,
    float* __restrict__ out)
{
  __shared__ float Cs[121];
  const int p = blockIdx.x;
  const int t = threadIdx.x;
  if (t < 121) Cs[t] = Cmat[(size_t)p*CSTRIDE + t];
  __syncthreads();

  const int c = 4*t;
  float4 x[NN];
#pragma unroll
  for (int n = 0; n < NN; ++n)
    x[n] = *(const float4*)(streams + ((size_t)n*RR + p)*DD + c);

#pragma unroll
  for (int i = 0; i < NN; ++i) {
    float4 o = make_float4(0.f,0.f,0.f,0.f);
#pragma unroll
    for (int n = 0; n < NN; ++n) {
      float cc = Cs[i*NN+n];
      o.x = fmaf(cc, x[n].x, o.x);
      o.y = fmaf(cc, x[n].y, o.y);
      o.z = fmaf(cc, x[n].z, o.z);
      o.w = fmaf(cc, x[n].w, o.w);
    }
    *(float4*)(out + ((size_t)i*RR + p)*DD + c) = o;
  }
}

extern "C" void kernel_launch(void* const* d_in, const int* in_sizes, int n_in,
                              void* d_out, int out_size, void* d_ws, size_t ws_size,
                              hipStream_t stream) {
  const float* streams = (const float*)d_in[0];
  const float* aq = (const float*)d_in[1];
  const float* ag = (const float*)d_in[2];
  const float* ab = (const float*)d_in[3];
  const float* mq = (const float*)d_in[4];
  const float* mg = (const float*)d_in[5];
  const float* mb = (const float*)d_in[6];
  float* outp = (float*)d_out;

  float* wvec = (float*)d_ws;                         // 22*1024 floats
  float* scal = wvec + 2*NN*DD;                       // 44 floats
  float* Cmat = wvec + 2*NN*DD + 64;                  // RR*128 floats (~4.2 MB)

  prep_kernel<<<dim3(2*NN), dim3(PREP_TPB), 0, stream>>>(aq, ag, ab, mq, mg, mb, wvec, scal);
  pos_kernel<<<dim3(RR), dim3(K1_TPB), 0, stream>>>(streams, wvec, scal, Cmat);
  combine_kernel<<<dim3(RR), dim3(K3_TPB), 0, stream>>>(streams, Cmat, outp);
}

// Round 3
// 398.245 us; speedup vs baseline: 1.2275x; 1.2228x over previous
//
#include <hip/hip_runtime.h>
#include <math.h>

#define NN 11
#define RR 8192               // B*L positions
#define DD 1024
#define EPSV 1e-5f
#define PREP_TPB 256

// ---- ws layout (floats) ----
// wvec : [22][1024]      @ 0        (q*gamma; attn 0..10, mlp 0..10)
// scal : [22][2]         @ 22528    (sum(q*g), sum(q*b)); padded to 64
// wT   : [1024][32]      @ 22592    (transposed weights, j<22 valid)
// dots : [24][11][8192]  @ 55360    (j: 0..10 dA, 11..21 dM, 22 sum, 23 sumsq)
// pack : [8192][264]     @ 2218048  (per-pos: w1[121], lg2[121], Ahd[11], mu_h[11])
#define OFF_SCAL 22528
#define OFF_WT   22592
#define OFF_DOTS 55360
#define OFF_PACK 2218048

__device__ __forceinline__ float wave_reduce(float v) {
#pragma unroll
  for (int o = 32; o > 0; o >>= 1) v += __shfl_xor(v, o, 64);
  return v;
}

__device__ __forceinline__ float dot4(const float4 a, const float4 b) {
  return a.x*b.x + a.y*b.y + a.z*b.z + a.w*b.w;
}

__global__ __launch_bounds__(PREP_TPB) void prep_kernel(
    const float* __restrict__ aq, const float* __restrict__ ag, const float* __restrict__ ab,
    const float* __restrict__ mq, const float* __restrict__ mg, const float* __restrict__ mb,
    float* __restrict__ wvec, float* __restrict__ scal, float* __restrict__ wT)
{
  const int j = blockIdx.x;              // 0..21
  const float *q, *g, *bt;
  if (j < NN) { q = aq + (size_t)j*DD;      g = ag + (size_t)j*DD;      bt = ab + (size_t)j*DD; }
  else        { q = mq + (size_t)(j-NN)*DD; g = mg + (size_t)(j-NN)*DD; bt = mb + (size_t)(j-NN)*DD; }
  const int t = threadIdx.x;
  float sqg = 0.f, sqb = 0.f;
  for (int d = t; d < DD; d += PREP_TPB) {
    float qq = q[d];
    float w  = qq * g[d];
    wvec[(size_t)j*DD + d] = w;
    wT[(size_t)d*32 + j]   = w;
    sqg += w;
    sqb += qq * bt[d];
  }
  sqg = wave_reduce(sqg);
  sqb = wave_reduce(sqb);
  __shared__ float red[2][PREP_TPB/64];
  const int lane = t & 63, wid = t >> 6;
  if (lane == 0) { red[0][wid] = sqg; red[1][wid] = sqb; }
  __syncthreads();
  if (t == 0) {
    float a = 0.f, b2 = 0.f;
    for (int w = 0; w < PREP_TPB/64; ++w) { a += red[0][w]; b2 += red[1][w]; }
    scal[2*j]   = a;
    scal[2*j+1] = b2;
  }
}

// K1: one thread per row (n,p). 22 w-dots + sum + sumsq, K serial in-thread.
// wT reads are block-uniform -> scalar loads. No cross-lane ops at all.
__global__ __launch_bounds__(256) void dots_kernel(
    const float* __restrict__ streams, const float* __restrict__ wT,
    float* __restrict__ dots)
{
  const int n = blockIdx.x >> 5;                   // 352 blocks = 11 n * 32
  const int p = (blockIdx.x & 31)*256 + threadIdx.x;
  const float* row = streams + ((size_t)n*RR + p)*DD;

  float acc[22];
#pragma unroll
  for (int j = 0; j < 22; ++j) acc[j] = 0.f;
  float sum = 0.f, ssq = 0.f;

  // register double-buffer: 4 float4 (64B) in flight per thread
  float4 c0 = *(const float4*)(row +  0);
  float4 c1 = *(const float4*)(row +  4);
  float4 c2 = *(const float4*)(row +  8);
  float4 c3 = *(const float4*)(row + 12);

  for (int k0 = 0; k0 < DD; k0 += 16) {
    float4 n0, n1, n2, n3;
    if (k0 + 16 < DD) {
      n0 = *(const float4*)(row + k0 + 16);
      n1 = *(const float4*)(row + k0 + 20);
      n2 = *(const float4*)(row + k0 + 24);
      n3 = *(const float4*)(row + k0 + 28);
    }
    float xs[16] = {c0.x,c0.y,c0.z,c0.w, c1.x,c1.y,c1.z,c1.w,
                    c2.x,c2.y,c2.z,c2.w, c3.x,c3.y,c3.z,c3.w};
#pragma unroll
    for (int e = 0; e < 16; ++e) {
      float xv = xs[e];
      sum += xv;
      ssq  = fmaf(xv, xv, ssq);
      const float* wp = wT + (size_t)(k0 + e)*32;   // uniform across block
#pragma unroll
      for (int j = 0; j < 22; ++j) acc[j] = fmaf(xv, wp[j], acc[j]);
    }
    c0 = n0; c1 = n1; c2 = n2; c3 = n3;
  }

#pragma unroll
  for (int j = 0; j < 22; ++j)
    dots[((size_t)j*NN + n)*RR + p] = acc[j];
  dots[((size_t)22*NN + n)*RR + p] = sum;
  dots[((size_t)23*NN + n)*RR + p] = ssq;
}

// K2: one thread per position. Softmax pass-1 weights, pass-2 logit pieces.
__global__ __launch_bounds__(256) void coef_kernel(
    const float* __restrict__ dots, const float* __restrict__ scal,
    float* __restrict__ pack)
{
  const int p = blockIdx.x*256 + threadIdx.x;      // 8192 threads exactly
  float mu[NN], rs[NN];
#pragma unroll
  for (int n = 0; n < NN; ++n) {
    float s  = dots[((size_t)22*NN + n)*RR + p];
    float q2 = dots[((size_t)23*NN + n)*RR + p];
    mu[n] = s * (1.f/DD);
    rs[n] = rsqrtf(q2*(1.f/DD) - mu[n]*mu[n] + EPSV);
  }
  float* pk = pack + (size_t)p*264;
  for (int i = 0; i < NN; ++i) {                   // uniform runtime i
    const float qgA = scal[2*i],        qbA = scal[2*i+1];
    const float qgM = scal[2*(NN+i)],   qbM = scal[2*(NN+i)+1];
    float w1[NN];
    float mx = -3.0e38f;
#pragma unroll
    for (int n = 0; n < NN; ++n) if (n <= i) {
      float dA = dots[((size_t)i*NN + n)*RR + p];
      float lg = (dA - mu[n]*qgA)*rs[n] + qbA;
      w1[n] = lg;
      mx = fmaxf(mx, lg);
    }
    float S = 0.f;
#pragma unroll
    for (int n = 0; n < NN; ++n) if (n <= i) { float e = __expf(w1[n]-mx); w1[n] = e; S += e; }
    float inv = 1.f/S;
    float muh = 0.f, hd = 0.f;
#pragma unroll
    for (int n = 0; n < NN; ++n) if (n <= i) {
      w1[n] *= inv;
      float dM = dots[((size_t)(NN+i)*NN + n)*RR + p];
      muh += w1[n]*mu[n];
      hd  += w1[n]*dM;
      pk[i*NN + n] = w1[n];
      if (n < i) pk[121 + i*NN + n] = (dM - mu[n]*qgM)*rs[n] + qbM;
    }
    pk[242 + i] = hd - muh*qgM;
    pk[253 + i] = muh;
  }
}

// K3: one block per position: h sumsq (11 wave reduces), finish logits,
// build C row, combine to out. Streams read once, out written once.
__global__ __launch_bounds__(256) void combine_kernel(
    const float* __restrict__ streams,
    const float* __restrict__ pack,
    const float* __restrict__ scal,
    float* __restrict__ out)
{
  __shared__ float P[264];
  __shared__ float red[4][12];
  __shared__ float C[121];

  const int p = blockIdx.x;
  const int t = threadIdx.x;
  const int lane = t & 63, w = t >> 6;

  for (int s = t; s < 264; s += 256) P[s] = pack[(size_t)p*264 + s];

  float4 x[NN];
#pragma unroll
  for (int n = 0; n < NN; ++n)
    x[n] = *(const float4*)(streams + ((size_t)n*RR + p)*DD + 4*t);
  __syncthreads();

  // h sumsq per i
  float hss[NN];
#pragma unroll
  for (int i = 0; i < NN; ++i) {
    float4 h = make_float4(0.f,0.f,0.f,0.f);
#pragma unroll
    for (int n = 0; n < NN; ++n) if (n <= i) {
      float wv = P[i*NN + n];
      h.x = fmaf(wv, x[n].x, h.x);
      h.y = fmaf(wv, x[n].y, h.y);
      h.z = fmaf(wv, x[n].z, h.z);
      h.w = fmaf(wv, x[n].w, h.w);
    }
    hss[i] = dot4(h, h);
  }
#pragma unroll
  for (int i = 0; i < NN; ++i) hss[i] = wave_reduce(hss[i]);
  if (lane == 0) {
#pragma unroll
    for (int i = 0; i < NN; ++i) red[w][i] = hss[i];
  }
  __syncthreads();

  if (t < NN) {
    const int i = t;
    float hs   = red[0][i] + red[1][i] + red[2][i] + red[3][i];
    float mu_h = P[253 + i];
    float Ahd  = P[242 + i];
    float varh = hs*(1.f/DD) - mu_h*mu_h;
    float rsh  = rsqrtf(varh + EPSV);
    float qbM  = scal[2*(NN+i)+1];
    float lgh  = Ahd*rsh + qbM;

    float mx2 = lgh;
#pragma unroll
    for (int n = 0; n < NN; ++n) if (n < i) mx2 = fmaxf(mx2, P[121 + i*NN + n]);
    float w2[NN];
    float eh = __expf(lgh - mx2);
    float S2 = eh;
#pragma unroll
    for (int n = 0; n < NN; ++n) if (n < i) {
      float e = __expf(P[121 + i*NN + n] - mx2);
      w2[n] = e;
      S2 += e;
    }
    float inv2 = 1.f/S2;
    float ehw  = eh*inv2;
#pragma unroll
    for (int n = 0; n < NN; ++n) {
      float cc = 0.f;
      if (n < i)  cc = w2[n]*inv2;
      if (n <= i) cc += ehw*P[i*NN + n];
      C[i*NN + n] = cc;
    }
  }
  __syncthreads();

#pragma unroll
  for (int i = 0; i < NN; ++i) {
    float4 o = make_float4(0.f,0.f,0.f,0.f);
#pragma unroll
    for (int n = 0; n < NN; ++n) {
      float cc = C[i*NN + n];
      o.x = fmaf(cc, x[n].x, o.x);
      o.y = fmaf(cc, x[n].y, o.y);
      o.z = fmaf(cc, x[n].z, o.z);
      o.w = fmaf(cc, x[n].w, o.w);
    }
    *(float4*)(out + ((size_t)i*RR + p)*DD + 4*t) = o;
  }
}

extern "C" void kernel_launch(void* const* d_in, const int* in_sizes, int n_in,
                              void* d_out, int out_size, void* d_ws, size_t ws_size,
                              hipStream_t stream) {
  const float* streams = (const float*)d_in[0];
  const float* aq = (const float*)d_in[1];
  const float* ag = (const float*)d_in[2];
  const float* ab = (const float*)d_in[3];
  const float* mq = (const float*)d_in[4];
  const float* mg = (const float*)d_in[5];
  const float* mb = (const float*)d_in[6];
  float* outp = (float*)d_out;

  float* wsf  = (float*)d_ws;
  float* wvec = wsf;
  float* scal = wsf + OFF_SCAL;
  float* wT   = wsf + OFF_WT;
  float* dots = wsf + OFF_DOTS;
  float* pack = wsf + OFF_PACK;

  prep_kernel<<<dim3(2*NN), dim3(PREP_TPB), 0, stream>>>(aq, ag, ab, mq, mg, mb, wvec, scal, wT);
  dots_kernel<<<dim3(11*32), dim3(256), 0, stream>>>(streams, wT, dots);
  coef_kernel<<<dim3(RR/256), dim3(256), 0, stream>>>(dots, scal, pack);
  combine_kernel<<<dim3(RR), dim3(256), 0, stream>>>(streams, pack, scal, outp);
}